// Round 1
// 663.342 us; speedup vs baseline: 1.3407x; 1.3407x over previous
//
#include <hip/hip_runtime.h>
#include <math.h>

#define N_USERS 100000
#define N_ITEMS 50000
#define N_NODES 150000
#define EMB 64
#define NI 128
#define NUM_EDGES 4000000
#define NPAD 150016            // 586 * 256
#define NB 586                 // buckets of 256 nodes
#define BSTRIDE 8192           // fixed slots per bucket (mean 6827, sigma ~83)
#define ETILE 4096
#define EGRID ((NUM_EDGES + ETILE - 1) / ETILE)   // 977
#define NTILES (N_NODES / 16)  // 9375
#define SBLK ((NTILES + 7) / 8) // 1172 blocks x 8 waves = 9376 waves

typedef __attribute__((ext_vector_type(8))) short bf16x8;
typedef __attribute__((ext_vector_type(4))) float f32x4;

__device__ __forceinline__ unsigned short f2bf(float f) {
    unsigned int u = __float_as_uint(f);
    u += 0x7FFFu + ((u >> 16) & 1u);
    return (unsigned short)(u >> 16);
}
__device__ __forceinline__ float bflo(unsigned int u) { return __uint_as_float(u << 16); }
__device__ __forceinline__ float bfhi(unsigned int u) { return __uint_as_float(u & 0xFFFF0000u); }

// ---- bucket scatter: block-aggregated reservations into fixed-stride buckets ----

__global__ __launch_bounds__(256) void bucket_scatter(const int* __restrict__ h,
                                                      const int* __restrict__ t,
                                                      int* __restrict__ gcur,
                                                      unsigned int* __restrict__ ebuf) {
    __shared__ int lc[NB];
    __shared__ int lbase[NB];
    __shared__ int lcur[NB];
    int tid = threadIdx.x;
    for (int i = tid; i < NB; i += 256) lc[i] = 0;
    __syncthreads();
    int base = blockIdx.x * ETILE;
#pragma unroll
    for (int k = 0; k < ETILE / 256; ++k) {
        int idx = base + k * 256 + tid;
        if (idx < NUM_EDGES) atomicAdd(&lc[h[idx] >> 8], 1);
    }
    __syncthreads();
    for (int i = tid; i < NB; i += 256) {
        int c = lc[i];
        lbase[i] = c ? (i * BSTRIDE + atomicAdd(&gcur[i], c)) : 0;
        lcur[i] = 0;
    }
    __syncthreads();
#pragma unroll
    for (int k = 0; k < ETILE / 256; ++k) {
        int idx = base + k * 256 + tid;
        if (idx < NUM_EDGES) {
            int hh = h[idx], tt = t[idx];
            int b = hh >> 8;
            int p = lbase[b] + atomicAdd(&lcur[b], 1);
            int lim = b * BSTRIDE + BSTRIDE - 1;
            p = (p <= lim) ? p : lim;
            ebuf[p] = ((unsigned int)(hh & 255) << 18) | (unsigned int)tt;
        }
    }
}

// ---- per-bucket in-LDS counting sort -> row-sorted col, rmeta=(start,count), dinv ----

__global__ __launch_bounds__(256) void bucket_csr(const int* __restrict__ gcur,
                                                  unsigned int* __restrict__ ebuf,
                                                  int2* __restrict__ rmeta,
                                                  float* __restrict__ dinv) {
    __shared__ unsigned int in_s[BSTRIDE];
    __shared__ unsigned int out_s[BSTRIDE];
    __shared__ int cnt_s[256];
    __shared__ int base_s[256];
    __shared__ int sc[256];
    int b = blockIdx.x, tid = threadIdx.x;
    int s = b * BSTRIDE;
    int n = gcur[b];
    if (n > BSTRIDE) n = BSTRIDE;

    for (int i = tid; i < n; i += 256) in_s[i] = ebuf[s + i];
    cnt_s[tid] = 0;
    __syncthreads();
    for (int i = tid; i < n; i += 256) atomicAdd(&cnt_s[in_s[i] >> 18], 1);
    __syncthreads();

    int c = cnt_s[tid];
    sc[tid] = c;
    __syncthreads();
    for (int off = 1; off < 256; off <<= 1) {
        int tv = (tid >= off) ? sc[tid - off] : 0;
        __syncthreads();
        sc[tid] += tv;
        __syncthreads();
    }
    int excl = sc[tid] - c;
    base_s[tid] = excl;
    int node = (b << 8) + tid;
    rmeta[node] = make_int2(s + excl, c);
    dinv[node] = (c > 0) ? rsqrtf((float)c) : 0.0f;
    cnt_s[tid] = 0;
    __syncthreads();

    for (int i = tid; i < n; i += 256) {
        unsigned int q = in_s[i];
        int hl = (int)(q >> 18);
        int p = base_s[hl] + atomicAdd(&cnt_s[hl], 1);
        out_s[p] = q & 0x3FFFFu;    // pure t index
    }
    __syncthreads();
    for (int i = tid; i < n; i += 256) ebuf[s + i] = out_s[i];
}

// ---- init: ebf = bf16(concat(user,item)); acc(d_out) = concat fp32 ----

__global__ void init_kernel(const float4* __restrict__ ue4, const float4* __restrict__ ie4,
                            uint2* __restrict__ ebf4, float4* __restrict__ out4) {
    int i = blockIdx.x * blockDim.x + threadIdx.x;
    const int uelems = N_USERS * EMB / 4;
    const int total  = N_NODES * EMB / 4;
    if (i < total) {
        float4 v = (i < uelems) ? ue4[i] : ie4[i - uelems];
        out4[i] = v;
        unsigned int p0 = ((unsigned int)f2bf(v.y) << 16) | f2bf(v.x);
        unsigned int p1 = ((unsigned int)f2bf(v.w) << 16) | f2bf(v.z);
        ebf4[i] = make_uint2(p0, p1);
    }
}

// ---- fused SpMM + MFMA intent head ----
// One 16-row tile per wave. Block = 512 (8 waves). LDS 80896 B -> 2 blocks/CU.
//
// Gather:  lane = (q = edge slot 0..3, c = dim quad 0..15); uint2 loads fetch
//          4 dims x 4 edges per instruction; 8 edges in flight, col prefetched.
//          Result (row-scaled) -> gnn LDS [16][68] f32 (stride 68: conflict-free).
// Matmul1: S[16x128] = E @ W via mfma_f32_16x16x32_bf16, 8 intent tiles x 2 K-steps.
//          A-frag: global dwordx4 from row-major bf16 table (row = c, k = 32s+8q).
//          B-frag: ds_read_b128 from W1s[intent][dim] (stride 72: even bank groups).
// Softmax: per C-reg row r (row = 4q+r), reduce over 8 tiles in-lane + shfl 1/2/4/8.
// Matmul2: O[16x64] = P @ W^T. P staged per 32-intent chunk in Pb [16][40] bf16,
//          hi/lo bf16 split (2 MFMA passes) keeps P at ~fp32 precision.
//          B-frag: ds_read_b128 from W2s[dim][intent] (stride 136: even bank groups).
// Epilogue: nv = gnn + O; ebfout = bf16(nv); acc = (acc + nv) * scale.

__global__ __launch_bounds__(512, 4) void spmm_intent(const int2* __restrict__ rmeta,
                                                      const unsigned int* __restrict__ col,
                                                      const float* __restrict__ dinv,
                                                      const unsigned short* __restrict__ ebf,
                                                      unsigned short* __restrict__ ebfout,
                                                      const float* __restrict__ W,
                                                      float* __restrict__ acc, float scale) {
    __shared__ __align__(16) unsigned short W1s[NI * 72];    // [intent][dim]  18432 B
    __shared__ __align__(16) unsigned short W2s[EMB * 136];  // [dim][intent]  17408 B
    __shared__ __align__(16) float gnns[8][16 * 68];         // 34816 B
    __shared__ __align__(16) unsigned short Pbs[8][16 * 40]; // 10240 B

    int tid = threadIdx.x;

    // stage W in both layouts (bf16), once per block
    const float4* W4 = (const float4*)W;
#pragma unroll
    for (int k = 0; k < 4; ++k) {
        int f = tid + k * 512;                // 2048 float4 = 64x128 f32
        float4 v = W4[f];
        int d = f >> 5, c4 = (f & 31) << 2;
        unsigned short bx = f2bf(v.x), by = f2bf(v.y), bz = f2bf(v.z), bw = f2bf(v.w);
        *(unsigned int*)&W2s[d * 136 + c4]     = (unsigned int)bx | ((unsigned int)by << 16);
        *(unsigned int*)&W2s[d * 136 + c4 + 2] = (unsigned int)bz | ((unsigned int)bw << 16);
        W1s[(c4 + 0) * 72 + d] = bx;
        W1s[(c4 + 1) * 72 + d] = by;
        W1s[(c4 + 2) * 72 + d] = bz;
        W1s[(c4 + 3) * 72 + d] = bw;
    }
    __syncthreads();

    int wid = tid >> 6, lane = tid & 63;
    int q = lane >> 4, c = lane & 15;
    int tile = blockIdx.x * 8 + wid;
    if (tile >= NTILES) return;
    int rowbase = tile << 4;
    float* gw = gnns[wid];
    unsigned short* pw = Pbs[wid];

    // ---- gather phase: 16 rows, 4 edges per load, 8 in flight ----
    for (int j = 0; j < 16; ++j) {
        int row = rowbase + j;
        int2 rm = rmeta[row];
        int s = rm.x, e = rm.x + rm.y;
        float a0 = 0.f, a1 = 0.f, a2 = 0.f, a3 = 0.f;
        float b0 = 0.f, b1 = 0.f, b2 = 0.f, b3 = 0.f;
        if (e > s) {
            int last = e - 1;
            int iA = s + q, iB = s + 4 + q;
            int ceA = (int)col[iA <= last ? iA : last];
            int ceB = (int)col[iB <= last ? iB : last];
            for (int i = s; i < e; i += 8) {
                int jA = i + q, jB = i + 4 + q;
                float gA = (jA < e) ? dinv[ceA] : 0.0f;
                float gB = (jB < e) ? dinv[ceB] : 0.0f;
                uint2 uA = *(const uint2*)(ebf + ((size_t)ceA << 6) + (c << 2));
                uint2 uB = *(const uint2*)(ebf + ((size_t)ceB << 6) + (c << 2));
                int nA = i + 8 + q, nB = i + 12 + q;
                ceA = (int)col[nA <= last ? nA : last];
                ceB = (int)col[nB <= last ? nB : last];
                a0 = fmaf(gA, bflo(uA.x), a0); a1 = fmaf(gA, bfhi(uA.x), a1);
                a2 = fmaf(gA, bflo(uA.y), a2); a3 = fmaf(gA, bfhi(uA.y), a3);
                b0 = fmaf(gB, bflo(uB.x), b0); b1 = fmaf(gB, bfhi(uB.x), b1);
                b2 = fmaf(gB, bflo(uB.y), b2); b3 = fmaf(gB, bfhi(uB.y), b3);
            }
        }
        a0 += b0; a1 += b1; a2 += b2; a3 += b3;
        a0 += __shfl_xor(a0, 16); a0 += __shfl_xor(a0, 32);
        a1 += __shfl_xor(a1, 16); a1 += __shfl_xor(a1, 32);
        a2 += __shfl_xor(a2, 16); a2 += __shfl_xor(a2, 32);
        a3 += __shfl_xor(a3, 16); a3 += __shfl_xor(a3, 32);
        if (lane < 16) {
            float dr = dinv[row];
            float4 v = make_float4(a0 * dr, a1 * dr, a2 * dr, a3 * dr);
            *(float4*)&gw[j * 68 + (c << 2)] = v;   // dims 4c..4c+3 of row j
        }
    }

    // ---- matmul1: S = E @ W (A row = c, k = 32s + 8q + j) ----
    const unsigned short* erow = ebf + ((size_t)(rowbase + c) << 6);
    bf16x8 A0 = *(const bf16x8*)(erow + (q << 3));
    bf16x8 A1 = *(const bf16x8*)(erow + 32 + (q << 3));
    f32x4 S[8];
#pragma unroll
    for (int t = 0; t < 8; ++t) {
        bf16x8 B0 = *(const bf16x8*)&W1s[(16 * t + c) * 72 + (q << 3)];
        bf16x8 B1 = *(const bf16x8*)&W1s[(16 * t + c) * 72 + 32 + (q << 3)];
        f32x4 z = {0.f, 0.f, 0.f, 0.f};
        z = __builtin_amdgcn_mfma_f32_16x16x32_bf16(A0, B0, z, 0, 0, 0);
        S[t] = __builtin_amdgcn_mfma_f32_16x16x32_bf16(A1, B1, z, 0, 0, 0);
    }

    // ---- softmax over 128 intents, per C-row (row = 4q + r) ----
#pragma unroll
    for (int r = 0; r < 4; ++r) {
        float m = S[0][r];
#pragma unroll
        for (int t = 1; t < 8; ++t) m = fmaxf(m, S[t][r]);
        m = fmaxf(m, __shfl_xor(m, 1)); m = fmaxf(m, __shfl_xor(m, 2));
        m = fmaxf(m, __shfl_xor(m, 4)); m = fmaxf(m, __shfl_xor(m, 8));
        float sum = 0.f;
#pragma unroll
        for (int t = 0; t < 8; ++t) { float ex = __expf(S[t][r] - m); S[t][r] = ex; sum += ex; }
        sum += __shfl_xor(sum, 1); sum += __shfl_xor(sum, 2);
        sum += __shfl_xor(sum, 4); sum += __shfl_xor(sum, 8);
        float inv = 1.0f / sum;
#pragma unroll
        for (int t = 0; t < 8; ++t) S[t][r] *= inv;
    }

    // ---- matmul2: O = P @ W^T, hi/lo bf16 split of P ----
    f32x4 O0 = {0.f, 0.f, 0.f, 0.f}, O1 = O0, O2 = O0, O3 = O0;
#pragma unroll
    for (int s2 = 0; s2 < 4; ++s2) {
        // hi pass: round P to bf16, keep residual in S
#pragma unroll
        for (int h2 = 0; h2 < 2; ++h2) {
            int t = 2 * s2 + h2;
#pragma unroll
            for (int r = 0; r < 4; ++r) {
                float p = S[t][r];
                unsigned short b = f2bf(p);
                pw[(4 * q + r) * 40 + (h2 << 4) + c] = b;
                S[t][r] = p - bflo((unsigned int)b);
            }
        }
        bf16x8 Pf = *(const bf16x8*)&pw[c * 40 + (q << 3)];
        {
            bf16x8 Bf0 = *(const bf16x8*)&W2s[(c) * 136 + (s2 << 5) + (q << 3)];
            bf16x8 Bf1 = *(const bf16x8*)&W2s[(16 + c) * 136 + (s2 << 5) + (q << 3)];
            bf16x8 Bf2 = *(const bf16x8*)&W2s[(32 + c) * 136 + (s2 << 5) + (q << 3)];
            bf16x8 Bf3 = *(const bf16x8*)&W2s[(48 + c) * 136 + (s2 << 5) + (q << 3)];
            O0 = __builtin_amdgcn_mfma_f32_16x16x32_bf16(Pf, Bf0, O0, 0, 0, 0);
            O1 = __builtin_amdgcn_mfma_f32_16x16x32_bf16(Pf, Bf1, O1, 0, 0, 0);
            O2 = __builtin_amdgcn_mfma_f32_16x16x32_bf16(Pf, Bf2, O2, 0, 0, 0);
            O3 = __builtin_amdgcn_mfma_f32_16x16x32_bf16(Pf, Bf3, O3, 0, 0, 0);
        }
        // lo pass: residual
#pragma unroll
        for (int h2 = 0; h2 < 2; ++h2) {
            int t = 2 * s2 + h2;
#pragma unroll
            for (int r = 0; r < 4; ++r)
                pw[(4 * q + r) * 40 + (h2 << 4) + c] = f2bf(S[t][r]);
        }
        bf16x8 Pl = *(const bf16x8*)&pw[c * 40 + (q << 3)];
        {
            bf16x8 Bf0 = *(const bf16x8*)&W2s[(c) * 136 + (s2 << 5) + (q << 3)];
            bf16x8 Bf1 = *(const bf16x8*)&W2s[(16 + c) * 136 + (s2 << 5) + (q << 3)];
            bf16x8 Bf2 = *(const bf16x8*)&W2s[(32 + c) * 136 + (s2 << 5) + (q << 3)];
            bf16x8 Bf3 = *(const bf16x8*)&W2s[(48 + c) * 136 + (s2 << 5) + (q << 3)];
            O0 = __builtin_amdgcn_mfma_f32_16x16x32_bf16(Pl, Bf0, O0, 0, 0, 0);
            O1 = __builtin_amdgcn_mfma_f32_16x16x32_bf16(Pl, Bf1, O1, 0, 0, 0);
            O2 = __builtin_amdgcn_mfma_f32_16x16x32_bf16(Pl, Bf2, O2, 0, 0, 0);
            O3 = __builtin_amdgcn_mfma_f32_16x16x32_bf16(Pl, Bf3, O3, 0, 0, 0);
        }
    }

    // ---- epilogue: combine with gnn, write bf16 out + acc update ----
#pragma unroll
    for (int r = 0; r < 4; ++r) {
        int rloc = 4 * q + r;
        const float* gr = &gw[rloc * 68];
        size_t rbase = ((size_t)(rowbase + rloc) << 6);
        float nv0 = gr[c]      + O0[r];
        float nv1 = gr[16 + c] + O1[r];
        float nv2 = gr[32 + c] + O2[r];
        float nv3 = gr[48 + c] + O3[r];
        ebfout[rbase + c]      = f2bf(nv0);
        ebfout[rbase + 16 + c] = f2bf(nv1);
        ebfout[rbase + 32 + c] = f2bf(nv2);
        ebfout[rbase + 48 + c] = f2bf(nv3);
        acc[rbase + c]      = (acc[rbase + c]      + nv0) * scale;
        acc[rbase + 16 + c] = (acc[rbase + 16 + c] + nv1) * scale;
        acc[rbase + 32 + c] = (acc[rbase + 32 + c] + nv2) * scale;
        acc[rbase + 48 + c] = (acc[rbase + 48 + c] + nv3) * scale;
    }
}

// ---- launch ----

extern "C" void kernel_launch(void* const* d_in, const int* in_sizes, int n_in,
                              void* d_out, int out_size, void* d_ws, size_t ws_size,
                              hipStream_t stream) {
    const float* ue = (const float*)d_in[0];
    const float* ie = (const float*)d_in[1];
    const float* W  = (const float*)d_in[2];
    const int*   h  = (const int*)d_in[3];
    const int*   t  = (const int*)d_in[4];
    float* out = (float*)d_out;

    // workspace (4-byte units), ~60 MB total
    int*            gcur  = (int*)d_ws;                         // 1024 (NB used)
    int2*           rmeta = (int2*)(gcur + 1024);               // NPAD int2
    float*          dinv  = (float*)(rmeta + NPAD);             // NPAD
    unsigned int*   ebuf  = (unsigned int*)(dinv + NPAD);       // NB*BSTRIDE
    unsigned short* ebfA  = (unsigned short*)(ebuf + NB * BSTRIDE);   // NPAD*64 ushort
    unsigned short* ebfB  = ebfA + (size_t)NPAD * EMB;                // NPAD*64 ushort

    hipMemsetAsync(gcur, 0, NB * sizeof(int), stream);
    bucket_scatter<<<EGRID, 256, 0, stream>>>(h, t, gcur, ebuf);
    bucket_csr<<<NB, 256, 0, stream>>>(gcur, ebuf, rmeta, dinv);
    init_kernel<<<(N_NODES * EMB / 4 + 255) / 256, 256, 0, stream>>>(
        (const float4*)ue, (const float4*)ie, (uint2*)ebfA, (float4*)out);

    const unsigned int* col = ebuf;
    spmm_intent<<<SBLK, 512, 0, stream>>>(rmeta, col, dinv, ebfA, ebfB, W, out, 1.0f);
    spmm_intent<<<SBLK, 512, 0, stream>>>(rmeta, col, dinv, ebfB, ebfA, W, out, 1.0f / 3.0f);
}

// Round 2
// 435.928 us; speedup vs baseline: 2.0402x; 1.5217x over previous
//
#include <hip/hip_runtime.h>
#include <math.h>

#define N_USERS 100000
#define N_ITEMS 50000
#define N_NODES 150000
#define EMB 64
#define NI 128
#define NUM_EDGES 4000000
#define NPAD 150016            // 586 * 256
#define NB 586                 // buckets of 256 nodes
#define BSTRIDE 8192           // fixed slots per bucket (mean 6827, sigma ~83)
#define ETILE 4096
#define EGRID ((NUM_EDGES + ETILE - 1) / ETILE)   // 977
#define NTILES (N_NODES / 16)  // 9375
#define SBLK ((NTILES + 7) / 8) // 1172 blocks x 8 waves = 9376 waves

typedef __attribute__((ext_vector_type(8))) short bf16x8;
typedef __attribute__((ext_vector_type(4))) float f32x4;

__device__ __forceinline__ unsigned short f2bf(float f) {
    unsigned int u = __float_as_uint(f);
    u += 0x7FFFu + ((u >> 16) & 1u);
    return (unsigned short)(u >> 16);
}
__device__ __forceinline__ float bflo(unsigned int u) { return __uint_as_float(u << 16); }
__device__ __forceinline__ float bfhi(unsigned int u) { return __uint_as_float(u & 0xFFFF0000u); }

// ---- bucket scatter: block-aggregated reservations into fixed-stride buckets ----

__global__ __launch_bounds__(256) void bucket_scatter(const int* __restrict__ h,
                                                      const int* __restrict__ t,
                                                      int* __restrict__ gcur,
                                                      unsigned int* __restrict__ ebuf) {
    __shared__ int lc[NB];
    __shared__ int lbase[NB];
    __shared__ int lcur[NB];
    int tid = threadIdx.x;
    for (int i = tid; i < NB; i += 256) lc[i] = 0;
    __syncthreads();
    int base = blockIdx.x * ETILE;
#pragma unroll
    for (int k = 0; k < ETILE / 256; ++k) {
        int idx = base + k * 256 + tid;
        if (idx < NUM_EDGES) atomicAdd(&lc[h[idx] >> 8], 1);
    }
    __syncthreads();
    for (int i = tid; i < NB; i += 256) {
        int c = lc[i];
        lbase[i] = c ? (i * BSTRIDE + atomicAdd(&gcur[i], c)) : 0;
        lcur[i] = 0;
    }
    __syncthreads();
#pragma unroll
    for (int k = 0; k < ETILE / 256; ++k) {
        int idx = base + k * 256 + tid;
        if (idx < NUM_EDGES) {
            int hh = h[idx], tt = t[idx];
            int b = hh >> 8;
            int p = lbase[b] + atomicAdd(&lcur[b], 1);
            int lim = b * BSTRIDE + BSTRIDE - 1;
            p = (p <= lim) ? p : lim;
            ebuf[p] = ((unsigned int)(hh & 255) << 18) | (unsigned int)tt;
        }
    }
}

// ---- per-bucket in-LDS counting sort -> row-sorted col, rmeta=(start,count), dinv ----

__global__ __launch_bounds__(256) void bucket_csr(const int* __restrict__ gcur,
                                                  unsigned int* __restrict__ ebuf,
                                                  int2* __restrict__ rmeta,
                                                  float* __restrict__ dinv) {
    __shared__ unsigned int in_s[BSTRIDE];
    __shared__ unsigned int out_s[BSTRIDE];
    __shared__ int cnt_s[256];
    __shared__ int base_s[256];
    __shared__ int sc[256];
    int b = blockIdx.x, tid = threadIdx.x;
    int s = b * BSTRIDE;
    int n = gcur[b];
    if (n > BSTRIDE) n = BSTRIDE;

    for (int i = tid; i < n; i += 256) in_s[i] = ebuf[s + i];
    cnt_s[tid] = 0;
    __syncthreads();
    for (int i = tid; i < n; i += 256) atomicAdd(&cnt_s[in_s[i] >> 18], 1);
    __syncthreads();

    int c = cnt_s[tid];
    sc[tid] = c;
    __syncthreads();
    for (int off = 1; off < 256; off <<= 1) {
        int tv = (tid >= off) ? sc[tid - off] : 0;
        __syncthreads();
        sc[tid] += tv;
        __syncthreads();
    }
    int excl = sc[tid] - c;
    base_s[tid] = excl;
    int node = (b << 8) + tid;
    rmeta[node] = make_int2(s + excl, c);
    dinv[node] = (c > 0) ? rsqrtf((float)c) : 0.0f;
    cnt_s[tid] = 0;
    __syncthreads();

    for (int i = tid; i < n; i += 256) {
        unsigned int q = in_s[i];
        int hl = (int)(q >> 18);
        int p = base_s[hl] + atomicAdd(&cnt_s[hl], 1);
        out_s[p] = q & 0x3FFFFu;    // pure t index
    }
    __syncthreads();
    for (int i = tid; i < n; i += 256) ebuf[s + i] = out_s[i];
}

// ---- init: ebf = bf16(concat(user,item)); acc(d_out) = concat fp32 ----

__global__ void init_kernel(const float4* __restrict__ ue4, const float4* __restrict__ ie4,
                            uint2* __restrict__ ebf4, float4* __restrict__ out4) {
    int i = blockIdx.x * blockDim.x + threadIdx.x;
    const int uelems = N_USERS * EMB / 4;
    const int total  = N_NODES * EMB / 4;
    if (i < total) {
        float4 v = (i < uelems) ? ue4[i] : ie4[i - uelems];
        out4[i] = v;
        unsigned int p0 = ((unsigned int)f2bf(v.y) << 16) | f2bf(v.x);
        unsigned int p1 = ((unsigned int)f2bf(v.w) << 16) | f2bf(v.z);
        ebf4[i] = make_uint2(p0, p1);
    }
}

// ---- fused MFMA intent head + latency-optimized SpMM gather ----
// One 16-row tile per wave. Block = 512 (8 waves). LDS 52480 B -> 3 blocks/CU (24 waves).
//
// Phase order: matmul1 -> softmax -> matmul2 -> gather(+epilogue), so the gather
// buffer can union with the P staging buffer (per-wave, disjoint lifetimes).
//
// Matmul1: S[16x128] = E @ W via mfma_f32_16x16x32_bf16 (A from global ebf rows,
//          B from W1s[intent][dim], stride 72 ushorts).
// Softmax: per C-reg row, in-register + shfl 1/2/4/8.
// Matmul2: O[16x64] = P @ W^T, hi/lo bf16 split of P (full fp32 precision),
//          B from W2s[dim][intent] stride 136.
// Gather:  row-parallel: lane = (qq = row slot 0..7, cc = dim oct 0..7).
//          uint4 loads (8 dims / 16 B per lane), 2 edges per row per iter ->
//          16 edges in flight per wave; col+dinv prefetched one iter ahead;
//          NO cross-lane reduce (lane owns its row's dims end-to-end).
//          Two 8-row halves; each half: result -> union buf (stride 65 floats,
//          <=2-way banks), then the 32 lanes owning those O-rows run the epilogue.

__global__ __launch_bounds__(512, 6) void spmm_intent(const int2* __restrict__ rmeta,
                                                      const unsigned int* __restrict__ col,
                                                      const float* __restrict__ dinv,
                                                      const unsigned short* __restrict__ ebf,
                                                      unsigned short* __restrict__ ebfout,
                                                      const float* __restrict__ W,
                                                      float* __restrict__ acc, float scale) {
    __shared__ __align__(16) unsigned short W1s[NI * 72];    // [intent][dim]  18432 B
    __shared__ __align__(16) unsigned short W2s[EMB * 136];  // [dim][intent]  17408 B
    __shared__ __align__(16) float UPool[8][520];            // union: Pb (1280B) / gnn buf (2080B)

    int tid = threadIdx.x;

    // stage W in both layouts (bf16), once per block
    const float4* W4 = (const float4*)W;
#pragma unroll
    for (int k = 0; k < 4; ++k) {
        int f = tid + k * 512;                // 2048 float4 = 64x128 f32
        float4 v = W4[f];
        int d = f >> 5, c4 = (f & 31) << 2;
        unsigned short bx = f2bf(v.x), by = f2bf(v.y), bz = f2bf(v.z), bw = f2bf(v.w);
        *(unsigned int*)&W2s[d * 136 + c4]     = (unsigned int)bx | ((unsigned int)by << 16);
        *(unsigned int*)&W2s[d * 136 + c4 + 2] = (unsigned int)bz | ((unsigned int)bw << 16);
        W1s[(c4 + 0) * 72 + d] = bx;
        W1s[(c4 + 1) * 72 + d] = by;
        W1s[(c4 + 2) * 72 + d] = bz;
        W1s[(c4 + 3) * 72 + d] = bw;
    }
    __syncthreads();

    int wid = tid >> 6, lane = tid & 63;
    int q = lane >> 4, c = lane & 15;        // matmul decomposition
    int qq = lane >> 3, cc = lane & 7;       // gather decomposition
    int tile = blockIdx.x * 8 + wid;
    if (tile >= NTILES) return;
    int rowbase = tile << 4;
    unsigned short* pw = (unsigned short*)&UPool[wid][0];
    float* fw = &UPool[wid][0];

    // ---- matmul1: S = E @ W (A row = c, k = 32s + 8q + j) ----
    const unsigned short* erow = ebf + ((size_t)(rowbase + c) << 6);
    bf16x8 A0 = *(const bf16x8*)(erow + (q << 3));
    bf16x8 A1 = *(const bf16x8*)(erow + 32 + (q << 3));
    f32x4 S[8];
#pragma unroll
    for (int t = 0; t < 8; ++t) {
        bf16x8 B0 = *(const bf16x8*)&W1s[(16 * t + c) * 72 + (q << 3)];
        bf16x8 B1 = *(const bf16x8*)&W1s[(16 * t + c) * 72 + 32 + (q << 3)];
        f32x4 z = {0.f, 0.f, 0.f, 0.f};
        z = __builtin_amdgcn_mfma_f32_16x16x32_bf16(A0, B0, z, 0, 0, 0);
        S[t] = __builtin_amdgcn_mfma_f32_16x16x32_bf16(A1, B1, z, 0, 0, 0);
    }

    // ---- softmax over 128 intents, per C-row (row = 4q + r) ----
#pragma unroll
    for (int r = 0; r < 4; ++r) {
        float m = S[0][r];
#pragma unroll
        for (int t = 1; t < 8; ++t) m = fmaxf(m, S[t][r]);
        m = fmaxf(m, __shfl_xor(m, 1)); m = fmaxf(m, __shfl_xor(m, 2));
        m = fmaxf(m, __shfl_xor(m, 4)); m = fmaxf(m, __shfl_xor(m, 8));
        float sum = 0.f;
#pragma unroll
        for (int t = 0; t < 8; ++t) { float ex = __expf(S[t][r] - m); S[t][r] = ex; sum += ex; }
        sum += __shfl_xor(sum, 1); sum += __shfl_xor(sum, 2);
        sum += __shfl_xor(sum, 4); sum += __shfl_xor(sum, 8);
        float inv = 1.0f / sum;
#pragma unroll
        for (int t = 0; t < 8; ++t) S[t][r] *= inv;
    }

    // ---- matmul2: O = P @ W^T, hi/lo bf16 split of P ----
    f32x4 O0 = {0.f, 0.f, 0.f, 0.f}, O1 = O0, O2 = O0, O3 = O0;
#pragma unroll
    for (int s2 = 0; s2 < 4; ++s2) {
#pragma unroll
        for (int h2 = 0; h2 < 2; ++h2) {
            int t = 2 * s2 + h2;
#pragma unroll
            for (int r = 0; r < 4; ++r) {
                float p = S[t][r];
                unsigned short b = f2bf(p);
                pw[(4 * q + r) * 40 + (h2 << 4) + c] = b;
                S[t][r] = p - bflo((unsigned int)b);
            }
        }
        bf16x8 Pf = *(const bf16x8*)&pw[c * 40 + (q << 3)];
        {
            bf16x8 Bf0 = *(const bf16x8*)&W2s[(c) * 136 + (s2 << 5) + (q << 3)];
            bf16x8 Bf1 = *(const bf16x8*)&W2s[(16 + c) * 136 + (s2 << 5) + (q << 3)];
            bf16x8 Bf2 = *(const bf16x8*)&W2s[(32 + c) * 136 + (s2 << 5) + (q << 3)];
            bf16x8 Bf3 = *(const bf16x8*)&W2s[(48 + c) * 136 + (s2 << 5) + (q << 3)];
            O0 = __builtin_amdgcn_mfma_f32_16x16x32_bf16(Pf, Bf0, O0, 0, 0, 0);
            O1 = __builtin_amdgcn_mfma_f32_16x16x32_bf16(Pf, Bf1, O1, 0, 0, 0);
            O2 = __builtin_amdgcn_mfma_f32_16x16x32_bf16(Pf, Bf2, O2, 0, 0, 0);
            O3 = __builtin_amdgcn_mfma_f32_16x16x32_bf16(Pf, Bf3, O3, 0, 0, 0);
        }
#pragma unroll
        for (int h2 = 0; h2 < 2; ++h2) {
            int t = 2 * s2 + h2;
#pragma unroll
            for (int r = 0; r < 4; ++r)
                pw[(4 * q + r) * 40 + (h2 << 4) + c] = f2bf(S[t][r]);
        }
        bf16x8 Pl = *(const bf16x8*)&pw[c * 40 + (q << 3)];
        {
            bf16x8 Bf0 = *(const bf16x8*)&W2s[(c) * 136 + (s2 << 5) + (q << 3)];
            bf16x8 Bf1 = *(const bf16x8*)&W2s[(16 + c) * 136 + (s2 << 5) + (q << 3)];
            bf16x8 Bf2 = *(const bf16x8*)&W2s[(32 + c) * 136 + (s2 << 5) + (q << 3)];
            bf16x8 Bf3 = *(const bf16x8*)&W2s[(48 + c) * 136 + (s2 << 5) + (q << 3)];
            O0 = __builtin_amdgcn_mfma_f32_16x16x32_bf16(Pl, Bf0, O0, 0, 0, 0);
            O1 = __builtin_amdgcn_mfma_f32_16x16x32_bf16(Pl, Bf1, O1, 0, 0, 0);
            O2 = __builtin_amdgcn_mfma_f32_16x16x32_bf16(Pl, Bf2, O2, 0, 0, 0);
            O3 = __builtin_amdgcn_mfma_f32_16x16x32_bf16(Pl, Bf3, O3, 0, 0, 0);
        }
    }

    // compiler fence: all Pb (ushort) LDS reads complete in program order before
    // the union region is reused as the float gather buffer
    asm volatile("" ::: "memory");

    // ---- gather + epilogue, two 8-row halves ----
#pragma unroll 1
    for (int half = 0; half < 2; ++half) {
        int row = rowbase + half * 8 + qq;
        int2 rm = rmeta[row];
        int s = rm.x, deg = rm.y;
        float dr = dinv[row];
        int dm = deg;
        dm = max(dm, __shfl_xor(dm, 8));
        dm = max(dm, __shfl_xor(dm, 16));
        dm = max(dm, __shfl_xor(dm, 32));
        dm = __builtin_amdgcn_readfirstlane(dm);

        float a0 = 0.f, a1 = 0.f, a2 = 0.f, a3 = 0.f;
        float a4 = 0.f, a5 = 0.f, a6 = 0.f, a7 = 0.f;
        int last = s + ((deg > 0) ? (deg - 1) : 0);
        int i1 = s + 1; if (i1 > last) i1 = last;
        int ce0 = (int)col[s];
        int ce1 = (int)col[i1];
        float g0 = dinv[ce0], g1 = dinv[ce1];
        const unsigned short* eb = ebf + (cc << 3);
        for (int it = 0; it < dm; it += 2) {
            float gu0 = (it < deg) ? g0 : 0.f;
            float gu1 = (it + 1 < deg) ? g1 : 0.f;
            uint4 u0 = *(const uint4*)(eb + ((size_t)ce0 << 6));
            uint4 u1 = *(const uint4*)(eb + ((size_t)ce1 << 6));
            int p0 = s + it + 2; if (p0 > last) p0 = last;
            int p1 = s + it + 3; if (p1 > last) p1 = last;
            ce0 = (int)col[p0]; ce1 = (int)col[p1];
            g0 = dinv[ce0]; g1 = dinv[ce1];
            a0 = fmaf(gu0, bflo(u0.x), a0); a1 = fmaf(gu0, bfhi(u0.x), a1);
            a2 = fmaf(gu0, bflo(u0.y), a2); a3 = fmaf(gu0, bfhi(u0.y), a3);
            a4 = fmaf(gu0, bflo(u0.z), a4); a5 = fmaf(gu0, bfhi(u0.z), a5);
            a6 = fmaf(gu0, bflo(u0.w), a6); a7 = fmaf(gu0, bfhi(u0.w), a7);
            a0 = fmaf(gu1, bflo(u1.x), a0); a1 = fmaf(gu1, bfhi(u1.x), a1);
            a2 = fmaf(gu1, bflo(u1.y), a2); a3 = fmaf(gu1, bfhi(u1.y), a3);
            a4 = fmaf(gu1, bflo(u1.z), a4); a5 = fmaf(gu1, bfhi(u1.z), a5);
            a6 = fmaf(gu1, bflo(u1.w), a6); a7 = fmaf(gu1, bfhi(u1.w), a7);
        }
        // store row-scaled partial (lane owns row qq, dims 8cc..8cc+7); stride 65
        int fb = qq * 65 + (cc << 3);
        fw[fb + 0] = a0 * dr; fw[fb + 1] = a1 * dr;
        fw[fb + 2] = a2 * dr; fw[fb + 3] = a3 * dr;
        fw[fb + 4] = a4 * dr; fw[fb + 5] = a5 * dr;
        fw[fb + 6] = a6 * dr; fw[fb + 7] = a7 * dr;

        // epilogue for this half: lanes whose O rows are 8*half..8*half+7
        if ((q >> 1) == half) {
            int qb = (q & 1) << 2;
#pragma unroll
            for (int r = 0; r < 4; ++r) {
                int rl = qb + r;                         // 0..7 within buf
                const float* gr = &fw[rl * 65];
                size_t rbase = ((size_t)(rowbase + half * 8 + rl) << 6);
                float nv0 = gr[c]      + O0[r];
                float nv1 = gr[16 + c] + O1[r];
                float nv2 = gr[32 + c] + O2[r];
                float nv3 = gr[48 + c] + O3[r];
                ebfout[rbase + c]      = f2bf(nv0);
                ebfout[rbase + 16 + c] = f2bf(nv1);
                ebfout[rbase + 32 + c] = f2bf(nv2);
                ebfout[rbase + 48 + c] = f2bf(nv3);
                acc[rbase + c]      = (acc[rbase + c]      + nv0) * scale;
                acc[rbase + 16 + c] = (acc[rbase + 16 + c] + nv1) * scale;
                acc[rbase + 32 + c] = (acc[rbase + 32 + c] + nv2) * scale;
                acc[rbase + 48 + c] = (acc[rbase + 48 + c] + nv3) * scale;
            }
        }
    }
}

// ---- launch ----

extern "C" void kernel_launch(void* const* d_in, const int* in_sizes, int n_in,
                              void* d_out, int out_size, void* d_ws, size_t ws_size,
                              hipStream_t stream) {
    const float* ue = (const float*)d_in[0];
    const float* ie = (const float*)d_in[1];
    const float* W  = (const float*)d_in[2];
    const int*   h  = (const int*)d_in[3];
    const int*   t  = (const int*)d_in[4];
    float* out = (float*)d_out;

    // workspace (4-byte units), ~60 MB total
    int*            gcur  = (int*)d_ws;                         // 1024 (NB used)
    int2*           rmeta = (int2*)(gcur + 1024);               // NPAD int2
    float*          dinv  = (float*)(rmeta + NPAD);             // NPAD
    unsigned int*   ebuf  = (unsigned int*)(dinv + NPAD);       // NB*BSTRIDE
    unsigned short* ebfA  = (unsigned short*)(ebuf + NB * BSTRIDE);   // NPAD*64 ushort
    unsigned short* ebfB  = ebfA + (size_t)NPAD * EMB;                // NPAD*64 ushort

    hipMemsetAsync(gcur, 0, NB * sizeof(int), stream);
    bucket_scatter<<<EGRID, 256, 0, stream>>>(h, t, gcur, ebuf);
    bucket_csr<<<NB, 256, 0, stream>>>(gcur, ebuf, rmeta, dinv);
    init_kernel<<<(N_NODES * EMB / 4 + 255) / 256, 256, 0, stream>>>(
        (const float4*)ue, (const float4*)ie, (uint2*)ebfA, (float4*)out);

    const unsigned int* col = ebuf;
    spmm_intent<<<SBLK, 512, 0, stream>>>(rmeta, col, dinv, ebfA, ebfB, W, out, 1.0f);
    spmm_intent<<<SBLK, 512, 0, stream>>>(rmeta, col, dinv, ebfB, ebfA, W, out, 1.0f / 3.0f);
}